// Round 4
// baseline (199.594 us; speedup 1.0000x reference)
//
#include <hip/hip_runtime.h>
#include <stdint.h>

// Problem constants: B=IC=16, L=4096, OC=256, NC=8, CD=16, K=9
#define IK_  144          // IC*K
// workspace layout (float element offsets)
#define WS_CW  0u                          // cw[nk=n*16+k][144]
#define WS_CB  18432u                      // cb[128]
#define WS_S0  18560u                      // s0[(m*128+nk)][4096]  (16.8 MB)
#define WS_UU  (WS_S0 + 8u*128u*4096u)     // U[nk][4096]           (2.1 MB)

// ---------------- K0: folded conv->caps weights ----------------
__global__ void k_cw(const float* __restrict__ caps_w,
                     const float* __restrict__ conv_w,
                     const float* __restrict__ conv_b,
                     const float* __restrict__ caps_b,
                     float* __restrict__ ws) {
    __shared__ float cwl[256];
    const int nk  = blockIdx.x;
    const int tid = threadIdx.x;
    cwl[tid] = caps_w[nk*256 + tid];
    __syncthreads();
    if (tid < IK_) {
        float a0 = 0.f, a1 = 0.f, a2 = 0.f, a3 = 0.f;
        for (int c = 0; c < 256; c += 4) {
            a0 += cwl[c+0] * conv_w[(c+0)*IK_ + tid];
            a1 += cwl[c+1] * conv_w[(c+1)*IK_ + tid];
            a2 += cwl[c+2] * conv_w[(c+2)*IK_ + tid];
            a3 += cwl[c+3] * conv_w[(c+3)*IK_ + tid];
        }
        ws[WS_CW + nk*IK_ + tid] = (a0 + a1) + (a2 + a3);
    } else if (tid == IK_) {
        float a = 0.f;
        for (int c = 0; c < 256; ++c) a += cwl[c] * conv_b[c];
        ws[WS_CB + nk] = a + caps_b[nk];
    }
}

// ---------------- K1: fused conv + c-mix ----------------
// block = (nk pair p: nkA=2p,nkB=2p+1; s-octant so: 512 s), 256 threads, 2 s/thread.
// For all 16 b: stage x[b,:,tile] in LDS, conv -> u, accumulate s0[m]=sum_b c[m,b,k]*u and U=sum_b u.
// LDS x tile: 16 rows x 520 floats (stride 528), row holds x[b,i, sbase-4 .. sbase+516), OOB = 0.
__global__ void __launch_bounds__(256) k_conv(const float* __restrict__ x,
                                              const float* __restrict__ wsc,
                                              const float* __restrict__ W,
                                              float* __restrict__ ws) {
    const int tid   = threadIdx.x;
    const int p     = blockIdx.x & 63;
    const int so    = blockIdx.x >> 6;       // 0..7
    const int sbase = so << 9;

    __shared__ float cwA[145], cwB[145];
    __shared__ float cl[2][8][16];           // c[half][m][b]
    __shared__ float xs[16*528];             // 33.8 KB

    for (int idx = tid; idx < 290; idx += 256) {
        const int which = idx >= 145;
        const int r = idx - which*145;
        const float v = (r < IK_) ? wsc[WS_CW + (2*p + which)*IK_ + r]
                                  : wsc[WS_CB + 2*p + which];
        (which ? cwB : cwA)[r] = v;
    }
    if (tid < 16) {                          // softmax over b of W[m,b,k], k per pair half
        const int half = tid >> 3, m = tid & 7;
        const int k = (2*p + half) & 15;
        float w[16], mx = -1e30f;
        #pragma unroll
        for (int b = 0; b < 16; ++b) {
            w[b] = W[m*256 + b*16 + k];
            mx = fmaxf(mx, w[b]);
        }
        float sum = 0.f;
        #pragma unroll
        for (int b = 0; b < 16; ++b) { w[b] = __expf(w[b] - mx); sum += w[b]; }
        const float inv = 1.f / sum;
        #pragma unroll
        for (int b = 0; b < 16; ++b) cl[half][m][b] = w[b] * inv;
    }

    float s0a[8][2], s0b[8][2], Ua[2], Ub[2];
    #pragma unroll
    for (int m = 0; m < 8; ++m) { s0a[m][0]=s0a[m][1]=s0b[m][0]=s0b[m][1]=0.f; }
    Ua[0]=Ua[1]=Ub[0]=Ub[1]=0.f;

    for (int b = 0; b < 16; ++b) {
        __syncthreads();                     // previous-b readers done (also covers cw/cl loads)
        // stage 16 rows x 130 float4
        for (int f = tid; f < 2080; f += 256) {
            const int row = f / 130;
            const int col = f - row*130;
            float4 v;
            const bool pad = (col == 0 && so == 0) || (col == 129 && so == 7);
            if (pad) v = make_float4(0.f,0.f,0.f,0.f);
            else     v = *(const float4*)(x + (b<<16) + (row<<12) + (sbase - 4 + (col<<2)));
            *(float4*)(xs + row*528 + (col<<2)) = v;
        }
        __syncthreads();

        float uA0=0.f, uA1=0.f, uB0=0.f, uB1=0.f;
        const float* wr = xs + 2*tid;        // window floats [2t .. 2t+9] of the padded row
        #pragma unroll
        for (int i = 0; i < 16; ++i) {
            const float* rw = wr + i*528;
            const float2 aa = *(const float2*)(rw);
            const float2 bb = *(const float2*)(rw+2);
            const float2 cc = *(const float2*)(rw+4);
            const float2 dd = *(const float2*)(rw+6);
            const float2 ee = *(const float2*)(rw+8);
            const float win[10] = {aa.x,aa.y,bb.x,bb.y,cc.x,cc.y,dd.x,dd.y,ee.x,ee.y};
            #pragma unroll
            for (int t = 0; t < 9; ++t) {
                const float wA = cwA[i*9+t], wB = cwB[i*9+t];
                uA0 = fmaf(wA, win[t],   uA0);
                uA1 = fmaf(wA, win[t+1], uA1);
                uB0 = fmaf(wB, win[t],   uB0);
                uB1 = fmaf(wB, win[t+1], uB1);
            }
        }
        const float cbA = cwA[144], cbB = cwB[144];
        uA0 += cbA; uA1 += cbA; uB0 += cbB; uB1 += cbB;
        Ua[0] += uA0; Ua[1] += uA1; Ub[0] += uB0; Ub[1] += uB1;
        #pragma unroll
        for (int m = 0; m < 8; ++m) {
            const float ca = cl[0][m][b], cb2 = cl[1][m][b];
            s0a[m][0] = fmaf(ca,  uA0, s0a[m][0]);
            s0a[m][1] = fmaf(ca,  uA1, s0a[m][1]);
            s0b[m][0] = fmaf(cb2, uB0, s0b[m][0]);
            s0b[m][1] = fmaf(cb2, uB1, s0b[m][1]);
        }
    }

    const int s = sbase + 2*tid;
    #pragma unroll
    for (int m = 0; m < 8; ++m) {
        *(float2*)(ws + WS_S0 + ((size_t)(m*128 + 2*p    ) << 12) + s) = make_float2(s0a[m][0], s0a[m][1]);
        *(float2*)(ws + WS_S0 + ((size_t)(m*128 + 2*p + 1) << 12) + s) = make_float2(s0b[m][0], s0b[m][1]);
    }
    *(float2*)(ws + WS_UU + ((size_t)(2*p    ) << 12) + s) = make_float2(Ua[0], Ua[1]);
    *(float2*)(ws + WS_UU + ((size_t)(2*p + 1) << 12) + s) = make_float2(Ub[0], Ub[1]);
}

// ---------------- block-wide sum over 256 threads ----------------
__device__ __forceinline__ float block_sum(float v, float* red, int tid) {
    #pragma unroll
    for (int off = 32; off; off >>= 1) v += __shfl_down(v, off, 64);
    if ((tid & 63) == 0) red[tid >> 6] = v;
    __syncthreads();
    const float r = (red[0] + red[1]) + (red[2] + red[3]);
    __syncthreads();
    return r;
}

// ---------------- K2: routing from s0/U. block = (m 0..7, nk 0..127) ----------------
// bx = m*128 + nk : same-nk blocks (sharing U row) land on the same XCD
__global__ void __launch_bounds__(256) k_route(const float* __restrict__ wsc,
                                               float* __restrict__ out) {
    const int tid = threadIdx.x;
    const int nk  = blockIdx.x & 127;
    const int m   = blockIdx.x >> 7;
    const int n   = nk >> 4, k = nk & 15;
    __shared__ float red[4];

    float sv[16], Uv[16];
    const float* ps = wsc + WS_S0 + ((size_t)(m*128 + nk) << 12) + (tid << 4);
    const float* pu = wsc + WS_UU + ((size_t)nk << 12) + (tid << 4);
    #pragma unroll
    for (int q = 0; q < 4; ++q) {
        float4 a = *(const float4*)(ps + 4*q);
        float4 b = *(const float4*)(pu + 4*q);
        sv[4*q+0]=a.x; sv[4*q+1]=a.y; sv[4*q+2]=a.z; sv[4*q+3]=a.w;
        Uv[4*q+0]=b.x; Uv[4*q+1]=b.y; Uv[4*q+2]=b.z; Uv[4*q+3]=b.w;
    }

    float p = 0.f;
    #pragma unroll
    for (int j = 0; j < 16; ++j) p = fmaf(sv[j], sv[j], p);
    const float n0 = block_sum(p, red, tid);
    const float r0 = __fsqrt_rn(n0) / (1.f + n0);

    float s1[16];
    p = 0.f;
    #pragma unroll
    for (int j = 0; j < 16; ++j) {
        s1[j] = sv[j] * fmaf(r0*sv[j], Uv[j], 1.f);
        p = fmaf(s1[j], s1[j], p);
    }
    const float n1 = block_sum(p, red, tid);
    const float r1 = __fsqrt_rn(n1) / (1.f + n1);

    p = 0.f;
    #pragma unroll
    for (int j = 0; j < 16; ++j) {
        s1[j] = fmaf(r1*s1[j]*s1[j], Uv[j], sv[j]);   // reuse as s2
        p = fmaf(s1[j], s1[j], p);
    }
    const float n2 = block_sum(p, red, tid);
    const float r2 = __fsqrt_rn(n2) / (1.f + n2);

    float4* po = (float4*)(out + ((size_t)((m*16 + k)*8 + n) << 12) + (tid << 4));
    #pragma unroll
    for (int q = 0; q < 4; ++q)
        po[q] = make_float4(s1[4*q+0]*r2, s1[4*q+1]*r2, s1[4*q+2]*r2, s1[4*q+3]*r2);
}

extern "C" void kernel_launch(void* const* d_in, const int* in_sizes, int n_in,
                              void* d_out, int out_size, void* d_ws, size_t ws_size,
                              hipStream_t stream) {
    const float* x      = (const float*)d_in[0];
    const float* conv_w = (const float*)d_in[1];
    const float* conv_b = (const float*)d_in[2];
    const float* caps_w = (const float*)d_in[3];
    const float* caps_b = (const float*)d_in[4];
    const float* W      = (const float*)d_in[5];
    float* ws  = (float*)d_ws;
    float* out = (float*)d_out;

    hipLaunchKernelGGL(k_cw,    dim3(128),  dim3(256), 0, stream, caps_w, conv_w, conv_b, caps_b, ws);
    hipLaunchKernelGGL(k_conv,  dim3(512),  dim3(256), 0, stream, x, ws, W, ws);
    hipLaunchKernelGGL(k_route, dim3(1024), dim3(256), 0, stream, ws, out);
}

// Round 5
// 142.803 us; speedup vs baseline: 1.3977x; 1.3977x over previous
//
#include <hip/hip_runtime.h>
#include <stdint.h>

// Problem constants: B=IC=16, L=4096, OC=256, NC=8, CD=16, K=9
#define IK_ 144
// workspace layout (float element offsets)
#define WS_CWT 0u          // cwT[(i*9+t)][nk]  : 144*128
#define WS_CB  18432u      // cb[128]
#define WS_U   18560u      // u[b][nk][s] at WS_U + ((b*128+nk)<<12) + s  (33.5 MB)

// ---------------- K0: folded conv->caps weights (transposed store) ----------------
// cwT[it][nk] = sum_c caps_w[nk,c]*conv_w[c,it];  cb[nk] = sum_c caps_w[nk,c]*conv_b[c] + caps_b[nk]
__global__ void k_cw(const float* __restrict__ caps_w,
                     const float* __restrict__ conv_w,
                     const float* __restrict__ conv_b,
                     const float* __restrict__ caps_b,
                     float* __restrict__ ws) {
    __shared__ float cwl[256];
    const int nk  = blockIdx.x;
    const int tid = threadIdx.x;
    cwl[tid] = caps_w[nk*256 + tid];
    __syncthreads();
    if (tid < IK_) {
        float a0 = 0.f, a1 = 0.f, a2 = 0.f, a3 = 0.f;
        for (int c = 0; c < 256; c += 4) {
            a0 += cwl[c+0] * conv_w[(c+0)*IK_ + tid];
            a1 += cwl[c+1] * conv_w[(c+1)*IK_ + tid];
            a2 += cwl[c+2] * conv_w[(c+2)*IK_ + tid];
            a3 += cwl[c+3] * conv_w[(c+3)*IK_ + tid];
        }
        ws[WS_CWT + tid*128 + nk] = (a0 + a1) + (a2 + a3);
    } else if (tid == IK_) {
        float a = 0.f;
        for (int c = 0; c < 256; ++c) a += cwl[c] * conv_b[c];
        ws[WS_CB + nk] = a + caps_b[nk];
    }
}

// ---------------- K1: u[b,nk,s] = conv(x[b], cw[nk]) + cb[nk] ----------------
// block = (stile 0..7 | oct 0..7 | b 0..15); bx%8 = b%8 -> same-b blocks share an XCD.
// 256 threads = 128 s-threads (4 s each) x 2 nk-halves (8 nk each). Stage x tile ONCE.
__global__ void __launch_bounds__(256) k_conv(const float* __restrict__ x,
                                              const float* __restrict__ wsc,
                                              float* __restrict__ ws) {
    const int tid   = threadIdx.x;
    const int b     = blockIdx.x & 15;
    const int oct   = (blockIdx.x >> 4) & 7;
    const int stile = blockIdx.x >> 7;
    const int sbase = stile << 9;

    __shared__ float xs[16*520];      // 16 rows, row j holds x[b,i, sbase-4+j], j in [0,520)
    __shared__ float cwT[144*16];     // [(i*9+t)][nkl]
    __shared__ float cbl[16];

    for (int idx = tid; idx < 2304; idx += 256) {
        const int it = idx >> 4, nkl = idx & 15;
        cwT[idx] = wsc[WS_CWT + it*128 + oct*16 + nkl];
    }
    if (tid < 16) cbl[tid] = wsc[WS_CB + oct*16 + tid];

    for (int f = tid; f < 2080; f += 256) {        // 16 rows x 130 float4
        const int row = f / 130;
        const int col = f - row*130;
        const int j0  = sbase + (col << 2) - 4;    // global s of first float (multiple of 4)
        float4 v;
        if (j0 < 0 || j0 > 4092) v = make_float4(0.f, 0.f, 0.f, 0.f);
        else v = *(const float4*)(x + (b << 16) + (row << 12) + j0);
        *(float4*)(xs + row*520 + (col << 2)) = v;
    }
    __syncthreads();

    const int sid  = tid & 127;
    const int half = tid >> 7;                     // wave-uniform
    float4 acc[8];
    #pragma unroll
    for (int q = 0; q < 8; ++q) acc[q] = make_float4(0.f, 0.f, 0.f, 0.f);

    #pragma unroll 4
    for (int i = 0; i < 16; ++i) {
        const float* rw = xs + i*520 + (sid << 2);
        const float4 w0 = ((const float4*)rw)[0];
        const float4 w1 = ((const float4*)rw)[1];
        const float4 w2 = ((const float4*)rw)[2];
        const float win[12] = {w0.x,w0.y,w0.z,w0.w, w1.x,w1.y,w1.z,w1.w, w2.x,w2.y,w2.z,w2.w};
        const float* cp = cwT + i*144 + half*8;
        #pragma unroll
        for (int t = 0; t < 9; ++t) {
            const float4 cA = *(const float4*)(cp + t*16);       // wave-uniform broadcast
            const float4 cB = *(const float4*)(cp + t*16 + 4);
            const float cv[8] = {cA.x,cA.y,cA.z,cA.w, cB.x,cB.y,cB.z,cB.w};
            #pragma unroll
            for (int q = 0; q < 8; ++q) {
                acc[q].x = fmaf(cv[q], win[t+0], acc[q].x);
                acc[q].y = fmaf(cv[q], win[t+1], acc[q].y);
                acc[q].z = fmaf(cv[q], win[t+2], acc[q].z);
                acc[q].w = fmaf(cv[q], win[t+3], acc[q].w);
            }
        }
    }

    const int s = sbase + (sid << 2);
    #pragma unroll
    for (int q = 0; q < 8; ++q) {
        const int nk = oct*16 + half*8 + q;
        const float cbv = cbl[half*8 + q];
        *(float4*)(ws + WS_U + ((size_t)((b << 7) + nk) << 12) + s) =
            make_float4(acc[q].x + cbv, acc[q].y + cbv, acc[q].z + cbv, acc[q].w + cbv);
    }
}

// ---------------- block-wide sum over 256 threads ----------------
__device__ __forceinline__ float block_sum(float v, float* red, int tid) {
    #pragma unroll
    for (int off = 32; off; off >>= 1) v += __shfl_down(v, off, 64);
    if ((tid & 63) == 0) red[tid >> 6] = v;
    __syncthreads();
    const float r = (red[0] + red[1]) + (red[2] + red[3]);
    __syncthreads();
    return r;
}

// ---------------- K2: c-mix + collapsed routing. block = (m 0..7, nk 0..127) ----------------
// bx = m*128 + nk : the 8 m-blocks of one nk share an XCD; per-XCD u working set = 4 MB = L2.
__global__ void __launch_bounds__(256) k_route(const float* __restrict__ wsc,
                                               const float* __restrict__ W,
                                               float* __restrict__ out) {
    const int tid = threadIdx.x;
    const int nk  = blockIdx.x & 127;
    const int m   = blockIdx.x >> 7;
    const int n   = nk >> 4, k = nk & 15;
    __shared__ float wl[16];
    __shared__ float red[4];
    if (tid < 16) wl[tid] = W[m*256 + tid*16 + k];
    __syncthreads();

    // softmax over b (redundant per thread; LDS broadcasts)
    float c[16], mx = -1e30f;
    #pragma unroll
    for (int b = 0; b < 16; ++b) { c[b] = wl[b]; mx = fmaxf(mx, c[b]); }
    float sum = 0.f;
    #pragma unroll
    for (int b = 0; b < 16; ++b) { c[b] = __expf(c[b] - mx); sum += c[b]; }
    const float inv = 1.f / sum;
    #pragma unroll
    for (int b = 0; b < 16; ++b) c[b] *= inv;

    float sv[16], Uv[16];
    #pragma unroll
    for (int j = 0; j < 16; ++j) { sv[j] = 0.f; Uv[j] = 0.f; }
    const float* ub = wsc + WS_U + (nk << 12) + (tid << 4);
    for (int b = 0; b < 16; ++b) {
        const float* p = ub + ((size_t)b << 19);   // b stride = 128*4096 floats
        float uv[16];
        #pragma unroll
        for (int q = 0; q < 4; ++q) {
            const float4 v = *(const float4*)(p + 4*q);
            uv[4*q+0]=v.x; uv[4*q+1]=v.y; uv[4*q+2]=v.z; uv[4*q+3]=v.w;
        }
        const float cb_ = c[b];
        #pragma unroll
        for (int j = 0; j < 16; ++j) {
            Uv[j] += uv[j];
            sv[j]  = fmaf(cb_, uv[j], sv[j]);
        }
    }

    float p = 0.f;
    #pragma unroll
    for (int j = 0; j < 16; ++j) p = fmaf(sv[j], sv[j], p);
    const float n0 = block_sum(p, red, tid);
    const float r0 = __fsqrt_rn(n0) / (1.f + n0);

    float s1[16];
    p = 0.f;
    #pragma unroll
    for (int j = 0; j < 16; ++j) {
        s1[j] = sv[j] * fmaf(r0*sv[j], Uv[j], 1.f);
        p = fmaf(s1[j], s1[j], p);
    }
    const float n1 = block_sum(p, red, tid);
    const float r1 = __fsqrt_rn(n1) / (1.f + n1);

    p = 0.f;
    #pragma unroll
    for (int j = 0; j < 16; ++j) {
        s1[j] = fmaf(r1*s1[j]*s1[j], Uv[j], sv[j]);   // reuse as s2
        p = fmaf(s1[j], s1[j], p);
    }
    const float n2 = block_sum(p, red, tid);
    const float r2 = __fsqrt_rn(n2) / (1.f + n2);

    float4* po = (float4*)(out + ((size_t)((m*16 + k)*8 + n) << 12) + (tid << 4));
    #pragma unroll
    for (int q = 0; q < 4; ++q)
        po[q] = make_float4(s1[4*q+0]*r2, s1[4*q+1]*r2, s1[4*q+2]*r2, s1[4*q+3]*r2);
}

extern "C" void kernel_launch(void* const* d_in, const int* in_sizes, int n_in,
                              void* d_out, int out_size, void* d_ws, size_t ws_size,
                              hipStream_t stream) {
    const float* x      = (const float*)d_in[0];
    const float* conv_w = (const float*)d_in[1];
    const float* conv_b = (const float*)d_in[2];
    const float* caps_w = (const float*)d_in[3];
    const float* caps_b = (const float*)d_in[4];
    const float* W      = (const float*)d_in[5];
    float* ws  = (float*)d_ws;
    float* out = (float*)d_out;

    hipLaunchKernelGGL(k_cw,    dim3(128),  dim3(256), 0, stream, caps_w, conv_w, conv_b, caps_b, ws);
    hipLaunchKernelGGL(k_conv,  dim3(1024), dim3(256), 0, stream, x, ws, ws);
    hipLaunchKernelGGL(k_route, dim3(1024), dim3(256), 0, stream, ws, W, out);
}

// Round 6
// 135.802 us; speedup vs baseline: 1.4697x; 1.0516x over previous
//
#include <hip/hip_runtime.h>
#include <stdint.h>

// Problem constants: B=IC=16, L=4096, OC=256, NC=8, CD=16, K=9
#define IK_ 144
// workspace layout (float element offsets)
#define WS_CWI 0u          // cwI[g=nk>>3][it=i*9+t][nk&7] : 16*144*8 = 18432
#define WS_CB  18432u      // cb[nk] (== cbI[g*8 + nk&7])
#define WS_U   18560u      // u[b][nk][s] at WS_U + ((b*128+nk)<<12) + s  (33.5 MB)

// ---------------- K0: folded conv->caps weights (nk-group-interleaved store) ----------------
// cwI[(nk>>3)][it][nk&7] = sum_c caps_w[nk,c]*conv_w[c,it]; cb[nk] = sum_c caps_w[nk,c]*conv_b[c]+caps_b[nk]
__global__ void k_cw(const float* __restrict__ caps_w,
                     const float* __restrict__ conv_w,
                     const float* __restrict__ conv_b,
                     const float* __restrict__ caps_b,
                     float* __restrict__ ws) {
    __shared__ float cwl[256];
    const int nk  = blockIdx.x;
    const int tid = threadIdx.x;
    cwl[tid] = caps_w[nk*256 + tid];
    __syncthreads();
    if (tid < IK_) {
        float a0 = 0.f, a1 = 0.f, a2 = 0.f, a3 = 0.f;
        for (int c = 0; c < 256; c += 4) {
            a0 += cwl[c+0] * conv_w[(c+0)*IK_ + tid];
            a1 += cwl[c+1] * conv_w[(c+1)*IK_ + tid];
            a2 += cwl[c+2] * conv_w[(c+2)*IK_ + tid];
            a3 += cwl[c+3] * conv_w[(c+3)*IK_ + tid];
        }
        ws[WS_CWI + (((nk >> 3)*IK_ + tid) << 3) + (nk & 7)] = (a0 + a1) + (a2 + a3);
    } else if (tid == IK_) {
        float a = 0.f;
        for (int c = 0; c < 256; ++c) a += cwl[c] * conv_b[c];
        ws[WS_CB + nk] = a + caps_b[nk];
    }
}

// ---------------- K1: u[b,nk,s] = conv(x[b], cw[nk]) + cb[nk] ----------------
// block = (stile 0..7 | oct 0..7 | b 0..15); bx%16=b -> same-b blocks cluster by XCD.
// 256 threads = 128 s-threads (4 s each) x 2 nk-halves (8 nk each). x tile staged ONCE in LDS;
// weights read via wave-uniform global loads -> SMEM scalar path (no LDS-pipe cost).
__global__ void __launch_bounds__(256) k_conv(const float* __restrict__ x,
                                              const float* __restrict__ wsc,
                                              float* __restrict__ ws) {
    const int tid   = threadIdx.x;
    const int b     = blockIdx.x & 15;
    const int oct   = (blockIdx.x >> 4) & 7;
    const int stile = blockIdx.x >> 7;
    const int sbase = stile << 9;

    __shared__ float xs[16*520];      // 16 rows, row j holds x[b,i, sbase-4+j], j in [0,520)

    for (int f = tid; f < 2080; f += 256) {        // 16 rows x 130 float4
        const int row = f / 130;
        const int col = f - row*130;
        const int j0  = sbase + (col << 2) - 4;    // global s of first float
        float4 v;
        if (j0 < 0 || j0 > 4092) v = make_float4(0.f, 0.f, 0.f, 0.f);
        else v = *(const float4*)(x + (b << 16) + (row << 12) + j0);
        *(float4*)(xs + row*520 + (col << 2)) = v;
    }
    __syncthreads();

    const int sid = tid & 127;
    const int g   = __builtin_amdgcn_readfirstlane(oct*2 + (tid >> 7));  // nk group of 8, wave-uniform
    const float* __restrict__ cwp = wsc + WS_CWI + g*(IK_ << 3);         // [it][8]
    const float* __restrict__ cbp = wsc + WS_CB  + (g << 3);

    float4 acc[8];
    #pragma unroll
    for (int q = 0; q < 8; ++q) acc[q] = make_float4(0.f, 0.f, 0.f, 0.f);

    #pragma unroll 2
    for (int i = 0; i < 16; ++i) {
        const float* rw = xs + i*520 + (sid << 2);
        const float4 w0 = ((const float4*)rw)[0];
        const float4 w1 = ((const float4*)rw)[1];
        const float4 w2 = ((const float4*)rw)[2];
        const float win[12] = {w0.x,w0.y,w0.z,w0.w, w1.x,w1.y,w1.z,w1.w, w2.x,w2.y,w2.z,w2.w};
        const float* cpi = cwp + i*72;             // 72 contiguous floats: [t][8]
        #pragma unroll
        for (int t = 0; t < 9; ++t) {
            #pragma unroll
            for (int q = 0; q < 8; ++q) {
                const float cv = cpi[t*8 + q];     // uniform -> s_load
                acc[q].x = fmaf(cv, win[t+0], acc[q].x);
                acc[q].y = fmaf(cv, win[t+1], acc[q].y);
                acc[q].z = fmaf(cv, win[t+2], acc[q].z);
                acc[q].w = fmaf(cv, win[t+3], acc[q].w);
            }
        }
    }

    const int s = sbase + (sid << 2);
    #pragma unroll
    for (int q = 0; q < 8; ++q) {
        const int nk = (g << 3) + q;
        const float cbv = cbp[q];                  // uniform -> s_load
        *(float4*)(ws + WS_U + ((size_t)((b << 7) + nk) << 12) + s) =
            make_float4(acc[q].x + cbv, acc[q].y + cbv, acc[q].z + cbv, acc[q].w + cbv);
    }
}

// ---------------- block-wide sum over 256 threads ----------------
__device__ __forceinline__ float block_sum(float v, float* red, int tid) {
    #pragma unroll
    for (int off = 32; off; off >>= 1) v += __shfl_down(v, off, 64);
    if ((tid & 63) == 0) red[tid >> 6] = v;
    __syncthreads();
    const float r = (red[0] + red[1]) + (red[2] + red[3]);
    __syncthreads();
    return r;
}

// ---------------- K2: c-mix + collapsed routing. block = (m 0..7, nk 0..127) ----------------
// bx = m*128 + nk : the 8 m-blocks of one nk share an XCD; per-XCD u working set = 4 MB = L2.
__global__ void __launch_bounds__(256) k_route(const float* __restrict__ wsc,
                                               const float* __restrict__ W,
                                               float* __restrict__ out) {
    const int tid = threadIdx.x;
    const int nk  = blockIdx.x & 127;
    const int m   = blockIdx.x >> 7;
    const int n   = nk >> 4, k = nk & 15;
    __shared__ float wl[16];
    __shared__ float red[4];
    if (tid < 16) wl[tid] = W[m*256 + tid*16 + k];
    __syncthreads();

    // softmax over b (redundant per thread; LDS broadcasts)
    float c[16], mx = -1e30f;
    #pragma unroll
    for (int b = 0; b < 16; ++b) { c[b] = wl[b]; mx = fmaxf(mx, c[b]); }
    float sum = 0.f;
    #pragma unroll
    for (int b = 0; b < 16; ++b) { c[b] = __expf(c[b] - mx); sum += c[b]; }
    const float inv = 1.f / sum;
    #pragma unroll
    for (int b = 0; b < 16; ++b) c[b] *= inv;

    float sv[16], Uv[16];
    #pragma unroll
    for (int j = 0; j < 16; ++j) { sv[j] = 0.f; Uv[j] = 0.f; }
    const float* ub = wsc + WS_U + (nk << 12) + (tid << 4);
    for (int b = 0; b < 16; ++b) {
        const float* p = ub + ((size_t)b << 19);   // b stride = 128*4096 floats
        float uv[16];
        #pragma unroll
        for (int q = 0; q < 4; ++q) {
            const float4 v = *(const float4*)(p + 4*q);
            uv[4*q+0]=v.x; uv[4*q+1]=v.y; uv[4*q+2]=v.z; uv[4*q+3]=v.w;
        }
        const float cb_ = c[b];
        #pragma unroll
        for (int j = 0; j < 16; ++j) {
            Uv[j] += uv[j];
            sv[j]  = fmaf(cb_, uv[j], sv[j]);
        }
    }

    float p = 0.f;
    #pragma unroll
    for (int j = 0; j < 16; ++j) p = fmaf(sv[j], sv[j], p);
    const float n0 = block_sum(p, red, tid);
    const float r0 = __fsqrt_rn(n0) / (1.f + n0);

    float s1[16];
    p = 0.f;
    #pragma unroll
    for (int j = 0; j < 16; ++j) {
        s1[j] = sv[j] * fmaf(r0*sv[j], Uv[j], 1.f);
        p = fmaf(s1[j], s1[j], p);
    }
    const float n1 = block_sum(p, red, tid);
    const float r1 = __fsqrt_rn(n1) / (1.f + n1);

    p = 0.f;
    #pragma unroll
    for (int j = 0; j < 16; ++j) {
        s1[j] = fmaf(r1*s1[j]*s1[j], Uv[j], sv[j]);   // reuse as s2
        p = fmaf(s1[j], s1[j], p);
    }
    const float n2 = block_sum(p, red, tid);
    const float r2 = __fsqrt_rn(n2) / (1.f + n2);

    float4* po = (float4*)(out + ((size_t)((m*16 + k)*8 + n) << 12) + (tid << 4));
    #pragma unroll
    for (int q = 0; q < 4; ++q)
        po[q] = make_float4(s1[4*q+0]*r2, s1[4*q+1]*r2, s1[4*q+2]*r2, s1[4*q+3]*r2);
}

extern "C" void kernel_launch(void* const* d_in, const int* in_sizes, int n_in,
                              void* d_out, int out_size, void* d_ws, size_t ws_size,
                              hipStream_t stream) {
    const float* x      = (const float*)d_in[0];
    const float* conv_w = (const float*)d_in[1];
    const float* conv_b = (const float*)d_in[2];
    const float* caps_w = (const float*)d_in[3];
    const float* caps_b = (const float*)d_in[4];
    const float* W      = (const float*)d_in[5];
    float* ws  = (float*)d_ws;
    float* out = (float*)d_out;

    hipLaunchKernelGGL(k_cw,    dim3(128),  dim3(256), 0, stream, caps_w, conv_w, conv_b, caps_b, ws);
    hipLaunchKernelGGL(k_conv,  dim3(1024), dim3(256), 0, stream, x, ws, ws);
    hipLaunchKernelGGL(k_route, dim3(1024), dim3(256), 0, stream, ws, W, out);
}

// Round 7
// 127.746 us; speedup vs baseline: 1.5624x; 1.0631x over previous
//
#include <hip/hip_runtime.h>
#include <hip/hip_bf16.h>
#include <stdint.h>

// Problem constants: B=IC=16, L=4096, OC=256, NC=8, CD=16, K=9
#define IK_ 144
// workspace layout (float element offsets)
#define WS_CWI 0u          // cwI[g=nk>>3][it=i*9+t][nk&7] : 16*144*8 = 18432 (fp32)
#define WS_CB  18432u      // cb[nk] (fp32)
#define WS_U   18560u      // u[b][nk][s] as bf16 at ((uint16_t*)(ws+WS_U)) + ((b*128+nk)<<12)+s  (16.7 MB)

__device__ __forceinline__ uint32_t pack2bf(float a, float b) {
    const uint32_t lo = (uint32_t)__bfloat16_as_ushort(__float2bfloat16(a));
    const uint32_t hi = (uint32_t)__bfloat16_as_ushort(__float2bfloat16(b));
    return lo | (hi << 16);
}
#define BFLO(u) __uint_as_float((u) << 16)
#define BFHI(u) __uint_as_float((u) & 0xffff0000u)

// ---------------- K0: folded conv->caps weights (nk-group-interleaved store) ----------------
__global__ void k_cw(const float* __restrict__ caps_w,
                     const float* __restrict__ conv_w,
                     const float* __restrict__ conv_b,
                     const float* __restrict__ caps_b,
                     float* __restrict__ ws) {
    __shared__ float cwl[256];
    const int nk  = blockIdx.x;
    const int tid = threadIdx.x;
    cwl[tid] = caps_w[nk*256 + tid];
    __syncthreads();
    if (tid < IK_) {
        float a0 = 0.f, a1 = 0.f, a2 = 0.f, a3 = 0.f;
        for (int c = 0; c < 256; c += 4) {
            a0 += cwl[c+0] * conv_w[(c+0)*IK_ + tid];
            a1 += cwl[c+1] * conv_w[(c+1)*IK_ + tid];
            a2 += cwl[c+2] * conv_w[(c+2)*IK_ + tid];
            a3 += cwl[c+3] * conv_w[(c+3)*IK_ + tid];
        }
        ws[WS_CWI + (((nk >> 3)*IK_ + tid) << 3) + (nk & 7)] = (a0 + a1) + (a2 + a3);
    } else if (tid == IK_) {
        float a = 0.f;
        for (int c = 0; c < 256; ++c) a += cwl[c] * conv_b[c];
        ws[WS_CB + nk] = a + caps_b[nk];
    }
}

// ---------------- K1: u[b,nk,s] = conv(x[b], cw[nk]) + cb[nk], stored bf16 ----------------
// block = (stile 0..7 | oct 0..7 | b 0..15). 256 threads = 128 s-threads (4 s) x 2 nk-halves (8 nk).
// x tile staged ONCE in LDS; weights via wave-uniform global loads -> SMEM scalar path.
__global__ void __launch_bounds__(256) k_conv(const float* __restrict__ x,
                                              const float* __restrict__ wsc,
                                              float* __restrict__ ws) {
    const int tid   = threadIdx.x;
    const int b     = blockIdx.x & 15;
    const int oct   = (blockIdx.x >> 4) & 7;
    const int stile = blockIdx.x >> 7;
    const int sbase = stile << 9;

    __shared__ float xs[16*520];      // 16 rows, row j holds x[b,i, sbase-4+j], j in [0,520)

    for (int f = tid; f < 2080; f += 256) {        // 16 rows x 130 float4
        const int row = f / 130;
        const int col = f - row*130;
        const int j0  = sbase + (col << 2) - 4;
        float4 v;
        if (j0 < 0 || j0 > 4092) v = make_float4(0.f, 0.f, 0.f, 0.f);
        else v = *(const float4*)(x + (b << 16) + (row << 12) + j0);
        *(float4*)(xs + row*520 + (col << 2)) = v;
    }
    __syncthreads();

    const int sid = tid & 127;
    const int g   = __builtin_amdgcn_readfirstlane(oct*2 + (tid >> 7));  // nk group of 8, wave-uniform
    const float* __restrict__ cwp = wsc + WS_CWI + g*(IK_ << 3);         // [it][8]
    const float* __restrict__ cbp = wsc + WS_CB  + (g << 3);

    float4 acc[8];
    #pragma unroll
    for (int q = 0; q < 8; ++q) acc[q] = make_float4(0.f, 0.f, 0.f, 0.f);

    #pragma unroll 2
    for (int i = 0; i < 16; ++i) {
        const float* rw = xs + i*520 + (sid << 2);
        const float4 w0 = ((const float4*)rw)[0];
        const float4 w1 = ((const float4*)rw)[1];
        const float4 w2 = ((const float4*)rw)[2];
        const float win[12] = {w0.x,w0.y,w0.z,w0.w, w1.x,w1.y,w1.z,w1.w, w2.x,w2.y,w2.z,w2.w};
        const float* cpi = cwp + i*72;             // 72 contiguous floats: [t][8]
        #pragma unroll
        for (int t = 0; t < 9; ++t) {
            #pragma unroll
            for (int q = 0; q < 8; ++q) {
                const float cv = cpi[t*8 + q];     // uniform -> s_load
                acc[q].x = fmaf(cv, win[t+0], acc[q].x);
                acc[q].y = fmaf(cv, win[t+1], acc[q].y);
                acc[q].z = fmaf(cv, win[t+2], acc[q].z);
                acc[q].w = fmaf(cv, win[t+3], acc[q].w);
            }
        }
    }

    const int s = sbase + (sid << 2);
    uint16_t* up = (uint16_t*)(ws + WS_U);
    #pragma unroll
    for (int q = 0; q < 8; ++q) {
        const int nk = (g << 3) + q;
        const float cbv = cbp[q];
        const uint32_t p0 = pack2bf(acc[q].x + cbv, acc[q].y + cbv);
        const uint32_t p1 = pack2bf(acc[q].z + cbv, acc[q].w + cbv);
        *(uint2*)(up + (((size_t)((b << 7) + nk)) << 12) + s) = make_uint2(p0, p1);
    }
}

// ---------------- block-wide sum over 256 threads ----------------
__device__ __forceinline__ float block_sum(float v, float* red, int tid) {
    #pragma unroll
    for (int off = 32; off; off >>= 1) v += __shfl_down(v, off, 64);
    if ((tid & 63) == 0) red[tid >> 6] = v;
    __syncthreads();
    const float r = (red[0] + red[1]) + (red[2] + red[3]);
    __syncthreads();
    return r;
}

// ---------------- K2: c-mix + collapsed routing. block = (m 0..7, nk 0..127) ----------------
// bx = m*128 + nk : the 8 m-blocks of one nk share an XCD; per-XCD bf16 u set = 2 MB (half an L2).
__global__ void __launch_bounds__(256) k_route(const float* __restrict__ wsc,
                                               const float* __restrict__ W,
                                               float* __restrict__ out) {
    const int tid = threadIdx.x;
    const int nk  = blockIdx.x & 127;
    const int m   = blockIdx.x >> 7;
    const int n   = nk >> 4, k = nk & 15;
    __shared__ float wl[16];
    __shared__ float red[4];
    if (tid < 16) wl[tid] = W[m*256 + tid*16 + k];
    __syncthreads();

    // softmax over b (redundant per thread; LDS broadcasts)
    float c[16], mx = -1e30f;
    #pragma unroll
    for (int b = 0; b < 16; ++b) { c[b] = wl[b]; mx = fmaxf(mx, c[b]); }
    float sum = 0.f;
    #pragma unroll
    for (int b = 0; b < 16; ++b) { c[b] = __expf(c[b] - mx); sum += c[b]; }
    const float inv = 1.f / sum;
    #pragma unroll
    for (int b = 0; b < 16; ++b) c[b] *= inv;

    float sv[16], Uv[16];
    #pragma unroll
    for (int j = 0; j < 16; ++j) { sv[j] = 0.f; Uv[j] = 0.f; }
    const uint16_t* ub = (const uint16_t*)(wsc + WS_U) + ((size_t)nk << 12) + (tid << 4);
    for (int b = 0; b < 16; ++b) {
        const uint16_t* p16 = ub + ((size_t)b << 19);     // b stride = 128*4096 elems
        const uint4 va = *(const uint4*)(p16);
        const uint4 vb = *(const uint4*)(p16 + 8);
        float uv[16];
        uv[0]=BFLO(va.x);  uv[1]=BFHI(va.x);  uv[2]=BFLO(va.y);  uv[3]=BFHI(va.y);
        uv[4]=BFLO(va.z);  uv[5]=BFHI(va.z);  uv[6]=BFLO(va.w);  uv[7]=BFHI(va.w);
        uv[8]=BFLO(vb.x);  uv[9]=BFHI(vb.x);  uv[10]=BFLO(vb.y); uv[11]=BFHI(vb.y);
        uv[12]=BFLO(vb.z); uv[13]=BFHI(vb.z); uv[14]=BFLO(vb.w); uv[15]=BFHI(vb.w);
        const float cb_ = c[b];
        #pragma unroll
        for (int j = 0; j < 16; ++j) {
            Uv[j] += uv[j];
            sv[j]  = fmaf(cb_, uv[j], sv[j]);
        }
    }

    float p = 0.f;
    #pragma unroll
    for (int j = 0; j < 16; ++j) p = fmaf(sv[j], sv[j], p);
    const float n0 = block_sum(p, red, tid);
    const float r0 = __fsqrt_rn(n0) / (1.f + n0);

    float s1[16];
    p = 0.f;
    #pragma unroll
    for (int j = 0; j < 16; ++j) {
        s1[j] = sv[j] * fmaf(r0*sv[j], Uv[j], 1.f);
        p = fmaf(s1[j], s1[j], p);
    }
    const float n1 = block_sum(p, red, tid);
    const float r1 = __fsqrt_rn(n1) / (1.f + n1);

    p = 0.f;
    #pragma unroll
    for (int j = 0; j < 16; ++j) {
        s1[j] = fmaf(r1*s1[j]*s1[j], Uv[j], sv[j]);   // reuse as s2
        p = fmaf(s1[j], s1[j], p);
    }
    const float n2 = block_sum(p, red, tid);
    const float r2 = __fsqrt_rn(n2) / (1.f + n2);

    float4* po = (float4*)(out + ((size_t)((m*16 + k)*8 + n) << 12) + (tid << 4));
    #pragma unroll
    for (int q = 0; q < 4; ++q)
        po[q] = make_float4(s1[4*q+0]*r2, s1[4*q+1]*r2, s1[4*q+2]*r2, s1[4*q+3]*r2);
}

extern "C" void kernel_launch(void* const* d_in, const int* in_sizes, int n_in,
                              void* d_out, int out_size, void* d_ws, size_t ws_size,
                              hipStream_t stream) {
    const float* x      = (const float*)d_in[0];
    const float* conv_w = (const float*)d_in[1];
    const float* conv_b = (const float*)d_in[2];
    const float* caps_w = (const float*)d_in[3];
    const float* caps_b = (const float*)d_in[4];
    const float* W      = (const float*)d_in[5];
    float* ws  = (float*)d_ws;
    float* out = (float*)d_out;

    hipLaunchKernelGGL(k_cw,    dim3(128),  dim3(256), 0, stream, caps_w, conv_w, conv_b, caps_b, ws);
    hipLaunchKernelGGL(k_conv,  dim3(1024), dim3(256), 0, stream, x, ws, ws);
    hipLaunchKernelGGL(k_route, dim3(1024), dim3(256), 0, stream, ws, W, out);
}

// Round 9
// 122.591 us; speedup vs baseline: 1.6281x; 1.0420x over previous
//
#include <hip/hip_runtime.h>
#include <hip/hip_bf16.h>
#include <stdint.h>

// Problem constants: B=IC=16, L=4096, OC=256, NC=8, CD=16, K=9
#define IK_ 144
typedef __fp16 h2 __attribute__((ext_vector_type(2)));

// workspace layout (float/dword element offsets)
#define WS_CWH 0u          // packed half2 weight pairs: [g=nk>>3][i][p][nk&7] : 16*16*5*8 = 10240 dwords
#define WS_CB  10240u      // cb[128] fp32
#define WS_U   10368u      // u[b][nk][s] bf16 at ((uint16_t*)(ws+WS_U)) + ((b*128+nk)<<12)+s (16.7 MB)

__device__ __forceinline__ uint32_t pack2bf(float a, float b) {
    const uint32_t lo = (uint32_t)__bfloat16_as_ushort(__float2bfloat16(a));
    const uint32_t hi = (uint32_t)__bfloat16_as_ushort(__float2bfloat16(b));
    return lo | (hi << 16);
}
#define BFLO(u) __uint_as_float((u) << 16)
#define BFHI(u) __uint_as_float((u) & 0xffff0000u)

// ---------------- K0: folded conv->caps weights, packed as half2 tap-pairs ----------------
// cw[nk,it] = sum_c caps_w[nk,c]*conv_w[c,it]; pairs (t=2p,2p+1), p=4 -> (t8, 0)
__global__ void k_cw(const float* __restrict__ caps_w,
                     const float* __restrict__ conv_w,
                     const float* __restrict__ conv_b,
                     const float* __restrict__ caps_b,
                     float* __restrict__ ws) {
    __shared__ float cwl[256];
    __shared__ float cwf[IK_];
    const int nk  = blockIdx.x;
    const int tid = threadIdx.x;
    cwl[tid] = caps_w[nk*256 + tid];
    __syncthreads();
    if (tid < IK_) {
        float a0 = 0.f, a1 = 0.f, a2 = 0.f, a3 = 0.f;
        for (int c = 0; c < 256; c += 4) {
            a0 += cwl[c+0] * conv_w[(c+0)*IK_ + tid];
            a1 += cwl[c+1] * conv_w[(c+1)*IK_ + tid];
            a2 += cwl[c+2] * conv_w[(c+2)*IK_ + tid];
            a3 += cwl[c+3] * conv_w[(c+3)*IK_ + tid];
        }
        cwf[tid] = (a0 + a1) + (a2 + a3);
    } else if (tid == IK_) {
        float a = 0.f;
        for (int c = 0; c < 256; ++c) a += cwl[c] * conv_b[c];
        ws[WS_CB + nk] = a + caps_b[nk];
    }
    __syncthreads();
    if (tid < 80) {                     // i = tid/5, p = tid%5
        const int i = tid / 5, p = tid - 5*i;
        const float w0 = cwf[i*9 + 2*p];
        const float w1 = (p < 4) ? cwf[i*9 + 2*p + 1] : 0.f;
        const h2 hp = __builtin_amdgcn_cvt_pkrtz(w0, w1);
        ((uint32_t*)ws)[WS_CWH + (((nk >> 3)*16 + i)*5 + p)*8 + (nk & 7)] =
            __builtin_bit_cast(uint32_t, hp);
    }
}

// ---------------- K1: u[b,nk,s] = conv(x[b], cw[nk]) + cb[nk], via v_dot2_f32_f16, bf16 store ----
// block = (stile 0..7 | oct 0..7 | b 0..15). 256 threads = 128 s-threads (4 s) x 2 nk-halves (8 nk).
// fp32 x tile staged ONCE in LDS; per-i window -> fp16 packed pairs in regs; weights via s_load.
__global__ void __launch_bounds__(256) k_conv(const float* __restrict__ x,
                                              const float* __restrict__ wsc,
                                              float* __restrict__ ws) {
    const int tid   = threadIdx.x;
    const int b     = blockIdx.x & 15;
    const int oct   = (blockIdx.x >> 4) & 7;
    const int stile = blockIdx.x >> 7;
    const int sbase = stile << 9;

    __shared__ float xs[16*528];      // row i, elem e <-> x[b,i, sbase-4+e], e in [0,528), OOB = 0

    for (int f = tid; f < 2112; f += 256) {        // 16 rows x 132 float4
        const int row = f / 132;
        const int col = f - row*132;
        const int j0  = sbase + (col << 2) - 4;
        float4 v;
        if (j0 < 0 || j0 > 4092) v = make_float4(0.f, 0.f, 0.f, 0.f);
        else v = *(const float4*)(x + (b << 16) + (row << 12) + j0);
        *(float4*)(xs + row*528 + (col << 2)) = v;
    }
    __syncthreads();

    const int sid = tid & 127;
    const int g   = __builtin_amdgcn_readfirstlane(oct*2 + (tid >> 7));  // nk group of 8, uniform
    const uint32_t* __restrict__ cwp = (const uint32_t*)wsc + WS_CWH + g*640;   // [i][p][8]
    const float*    __restrict__ cbp = wsc + WS_CB + (g << 3);

    float4 acc[8];
    #pragma unroll
    for (int q = 0; q < 8; ++q) acc[q] = make_float4(0.f, 0.f, 0.f, 0.f);

    #pragma unroll 2
    for (int i = 0; i < 16; ++i) {
        const float* rw = xs + i*528 + (sid << 2);
        const float4 w0 = ((const float4*)rw)[0];
        const float4 w1 = ((const float4*)rw)[1];
        const float4 w2 = ((const float4*)rw)[2];
        const float4 w3 = ((const float4*)rw)[3];
        const float f[14] = {w0.x,w0.y,w0.z,w0.w, w1.x,w1.y,w1.z,w1.w,
                             w2.x,w2.y,w2.z,w2.w, w3.x,w3.y};
        // E[d] = (f[2d], f[2d+1])  -> even-s operand pairs; O[d] = (f[2d+1], f[2d+2]) -> odd-s
        h2 E[6], O[6];
        #pragma unroll
        for (int d = 0; d < 6; ++d) {
            E[d] = __builtin_amdgcn_cvt_pkrtz(f[2*d],   f[2*d+1]);
            O[d] = __builtin_amdgcn_cvt_pkrtz(f[2*d+1], f[2*d+2]);
        }
        const uint32_t* cpi = cwp + i*40;
        #pragma unroll
        for (int q = 0; q < 8; ++q) {
            #pragma unroll
            for (int p = 0; p < 5; ++p) {
                const h2 wv = __builtin_bit_cast(h2, cpi[p*8 + q]);   // uniform -> s_load
                acc[q].x = __builtin_amdgcn_fdot2(wv, E[p],   acc[q].x, false);
                acc[q].y = __builtin_amdgcn_fdot2(wv, O[p],   acc[q].y, false);
                acc[q].z = __builtin_amdgcn_fdot2(wv, E[p+1], acc[q].z, false);
                acc[q].w = __builtin_amdgcn_fdot2(wv, O[p+1], acc[q].w, false);
            }
        }
    }

    const int s = sbase + (sid << 2);
    uint16_t* up = (uint16_t*)(ws + WS_U);
    #pragma unroll
    for (int q = 0; q < 8; ++q) {
        const int nk = (g << 3) + q;
        const float cbv = cbp[q];
        const uint32_t p0 = pack2bf(acc[q].x + cbv, acc[q].y + cbv);
        const uint32_t p1 = pack2bf(acc[q].z + cbv, acc[q].w + cbv);
        *(uint2*)(up + (((size_t)((b << 7) + nk)) << 12) + s) = make_uint2(p0, p1);
    }
}

// ---------------- block-wide sum over 256 threads ----------------
__device__ __forceinline__ float block_sum(float v, float* red, int tid) {
    #pragma unroll
    for (int off = 32; off; off >>= 1) v += __shfl_down(v, off, 64);
    if ((tid & 63) == 0) red[tid >> 6] = v;
    __syncthreads();
    const float r = (red[0] + red[1]) + (red[2] + red[3]);
    __syncthreads();
    return r;
}

// ---------------- K2: c-mix + collapsed routing. block = (m 0..7, nk 0..127) ----------------
// bx = m*128 + nk : the 8 m-blocks of one nk share an XCD; per-XCD bf16 u set = 2 MB (half an L2).
__global__ void __launch_bounds__(256) k_route(const float* __restrict__ wsc,
                                               const float* __restrict__ W,
                                               float* __restrict__ out) {
    const int tid = threadIdx.x;
    const int nk  = blockIdx.x & 127;
    const int m   = blockIdx.x >> 7;
    const int n   = nk >> 4, k = nk & 15;
    __shared__ float wl[16];
    __shared__ float red[4];
    if (tid < 16) wl[tid] = W[m*256 + tid*16 + k];
    __syncthreads();

    // softmax over b (redundant per thread; LDS broadcasts)
    float c[16], mx = -1e30f;
    #pragma unroll
    for (int b = 0; b < 16; ++b) { c[b] = wl[b]; mx = fmaxf(mx, c[b]); }
    float sum = 0.f;
    #pragma unroll
    for (int b = 0; b < 16; ++b) { c[b] = __expf(c[b] - mx); sum += c[b]; }
    const float inv = 1.f / sum;
    #pragma unroll
    for (int b = 0; b < 16; ++b) c[b] *= inv;

    float sv[16], Uv[16];
    #pragma unroll
    for (int j = 0; j < 16; ++j) { sv[j] = 0.f; Uv[j] = 0.f; }
    const uint16_t* ub = (const uint16_t*)(wsc + WS_U) + ((size_t)nk << 12) + (tid << 4);
    for (int b = 0; b < 16; ++b) {
        const uint16_t* p16 = ub + ((size_t)b << 19);     // b stride = 128*4096 elems
        const uint4 va = *(const uint4*)(p16);
        const uint4 vb = *(const uint4*)(p16 + 8);
        float uv[16];
        uv[0]=BFLO(va.x);  uv[1]=BFHI(va.x);  uv[2]=BFLO(va.y);  uv[3]=BFHI(va.y);
        uv[4]=BFLO(va.z);  uv[5]=BFHI(va.z);  uv[6]=BFLO(va.w);  uv[7]=BFHI(va.w);
        uv[8]=BFLO(vb.x);  uv[9]=BFHI(vb.x);  uv[10]=BFLO(vb.y); uv[11]=BFHI(vb.y);
        uv[12]=BFLO(vb.z); uv[13]=BFHI(vb.z); uv[14]=BFLO(vb.w); uv[15]=BFHI(vb.w);
        const float cb_ = c[b];
        #pragma unroll
        for (int j = 0; j < 16; ++j) {
            Uv[j] += uv[j];
            sv[j]  = fmaf(cb_, uv[j], sv[j]);
        }
    }

    float p = 0.f;
    #pragma unroll
    for (int j = 0; j < 16; ++j) p = fmaf(sv[j], sv[j], p);
    const float n0 = block_sum(p, red, tid);
    const float r0 = __fsqrt_rn(n0) / (1.f + n0);

    float s1[16];
    p = 0.f;
    #pragma unroll
    for (int j = 0; j < 16; ++j) {
        s1[j] = sv[j] * fmaf(r0*sv[j], Uv[j], 1.f);
        p = fmaf(s1[j], s1[j], p);
    }
    const float n1 = block_sum(p, red, tid);
    const float r1 = __fsqrt_rn(n1) / (1.f + n1);

    p = 0.f;
    #pragma unroll
    for (int j = 0; j < 16; ++j) {
        s1[j] = fmaf(r1*s1[j]*s1[j], Uv[j], sv[j]);   // reuse as s2
        p = fmaf(s1[j], s1[j], p);
    }
    const float n2 = block_sum(p, red, tid);
    const float r2 = __fsqrt_rn(n2) / (1.f + n2);

    float4* po = (float4*)(out + ((size_t)((m*16 + k)*8 + n) << 12) + (tid << 4));
    #pragma unroll
    for (int q = 0; q < 4; ++q)
        po[q] = make_float4(s1[4*q+0]*r2, s1[4*q+1]*r2, s1[4*q+2]*r2, s1[4*q+3]*r2);
}

extern "C" void kernel_launch(void* const* d_in, const int* in_sizes, int n_in,
                              void* d_out, int out_size, void* d_ws, size_t ws_size,
                              hipStream_t stream) {
    const float* x      = (const float*)d_in[0];
    const float* conv_w = (const float*)d_in[1];
    const float* conv_b = (const float*)d_in[2];
    const float* caps_w = (const float*)d_in[3];
    const float* caps_b = (const float*)d_in[4];
    const float* W      = (const float*)d_in[5];
    float* ws  = (float*)d_ws;
    float* out = (float*)d_out;

    hipLaunchKernelGGL(k_cw,    dim3(128),  dim3(256), 0, stream, caps_w, conv_w, conv_b, caps_b, ws);
    hipLaunchKernelGGL(k_conv,  dim3(1024), dim3(256), 0, stream, x, ws, ws);
    hipLaunchKernelGGL(k_route, dim3(1024), dim3(256), 0, stream, ws, W, out);
}